// Round 6
// baseline (22204.121 us; speedup 1.0000x reference)
//
#include <hip/hip_runtime.h>
#include <math.h>

// ---- problem dims ----
#define TN 64
#define BN 32
#define EPSF 1e-6f

// ---- compact workspace layout (floats): ping-pong H/RV, no history ----
constexpr long OFF_H     = 0;        // 2 slots * 32*1024
constexpr long OFF_RV    = OFF_H    + 65536;   // 2 slots * 32*256
constexpr long OFF_S     = OFF_RV   + 16384;   // 32768
constexpr long OFF_RW    = OFF_S    + 32768;   // B*N*HD = 16384
constexpr long OFF_WW    = OFF_RW   + 16384;   // B*N
constexpr long OFF_U     = OFF_WW   + 4096;
constexpr long OFF_P     = OFF_U    + 4096;
constexpr long OFF_MEM   = OFF_P    + 4096;    // B*N*WD = 262144
constexpr long OFF_LINKS = OFF_MEM  + 262144;  // B*N*N = 524288
constexpr long OFF_GATES = OFF_LINKS+ 524288;  // B*4096
constexpr long OFF_PROJ  = OFF_GATES+ 131072;  // B*512 (471 used)
constexpr long OFF_SRC   = OFF_PROJ + 16384;   // 2048 ints (decoded src)
// total ≈ 4.2 MB

__device__ __forceinline__ float sigm(float x) { return 1.f / (1.f + expf(-x)); }
__device__ __forceinline__ float oneplus_(float x) {
  return 1.f + fmaxf(x, 0.f) + log1pf(expf(-fabsf(x)));
}

// ===== src width auto-detect + decode to int32 =============================
__global__ void src_decode(const void* __restrict__ src_raw, float* __restrict__ ws) {
  __shared__ int is64_s;
  if (threadIdx.x == 0) is64_s = 1;
  __syncthreads();
  const long long* s64 = (const long long*)src_raw;
  for (int i = threadIdx.x; i < 1024; i += 256) {
    long long v = s64[i];
    if (v < 0 || v >= 32000) is64_s = 0;
  }
  __syncthreads();
  int* dst = (int*)(ws + OFF_SRC);
  if (is64_s) {
    for (int i = threadIdx.x; i < 2048; i += 256) dst[i] = (int)s64[i];
  } else {
    const int* s32 = (const int*)src_raw;
    for (int i = threadIdx.x; i < 2048; i += 256) dst[i] = s32[i];
  }
}

// ================= init: zero all state, U=EPS =================
__global__ void init_kernel(float* ws) {
  long i0 = (long)blockIdx.x * blockDim.x + threadIdx.x;
  long stride = (long)gridDim.x * blockDim.x;
  for (long x = i0; x < OFF_GATES; x += stride) {
    ws[x] = (x >= OFF_U && x < OFF_U + 4096) ? EPSF : 0.f;
  }
}

// ===== naive gates: one thread per (b,j) ============
__global__ __launch_bounds__(256) void gates_naive(
    int t, const float* __restrict__ emb,
    const float* __restrict__ W_ih, const float* __restrict__ W_hh,
    const float* __restrict__ b_ih, const float* __restrict__ b_hh,
    float* __restrict__ ws) {
  int i = blockIdx.x * 256 + threadIdx.x;   // 0..131071
  int b = i >> 12, j = i & 4095;
  const int* src = (const int*)(ws + OFF_SRC);
  const float* e  = emb + (long)src[t * 32 + b] * 512;
  const float* rv = ws + OFF_RV + (long)(t & 1) * 8192 + b * 256;
  const float* h  = ws + OFF_H  + (long)(t & 1) * 32768 + b * 1024;
  const float* wi = W_ih + (long)j * 768;
  const float* wh = W_hh + (long)j * 1024;
  float acc = b_ih[j] + b_hh[j];
#pragma unroll 4
  for (int k = 0; k < 512; k += 4) {
    float4 a = *(const float4*)(e + k);
    float4 w = *(const float4*)(wi + k);
    acc += a.x * w.x + a.y * w.y + a.z * w.z + a.w * w.w;
  }
#pragma unroll 4
  for (int k = 0; k < 256; k += 4) {
    float4 a = *(const float4*)(rv + k);
    float4 w = *(const float4*)(wi + 512 + k);
    acc += a.x * w.x + a.y * w.y + a.z * w.z + a.w * w.w;
  }
#pragma unroll 4
  for (int k = 0; k < 1024; k += 4) {
    float4 a = *(const float4*)(h + k);
    float4 w = *(const float4*)(wh + k);
    acc += a.x * w.x + a.y * w.y + a.z * w.z + a.w * w.w;
  }
  ws[OFF_GATES + (long)b * 4096 + j] = acc;
}

// ================= LSTM pointwise =================
__global__ void lstm_kernel(int t, float* __restrict__ ws) {
  int i = blockIdx.x * 256 + threadIdx.x;  // 0..32767
  int b = i >> 10, j = i & 1023;
  const float* g = ws + OFF_GATES + b * 4096;
  float gi = g[j], gf = g[1024 + j], gg = g[2048 + j], go = g[3072 + j];
  float sv = sigm(gf) * ws[OFF_S + i] + sigm(gi) * tanhf(gg);
  ws[OFF_S + i] = sv;
  ws[OFF_H + (long)((t + 1) & 1) * 32768 + i] = sigm(go) * tanhf(sv);
}

// ===== naive proj: one thread per (o,b) ===========
__global__ __launch_bounds__(256) void proj_naive(
    int t, float* __restrict__ ws,
    const float* rk_w, const float* rk_b, const float* rs_w, const float* rs_b,
    const float* fg_w, const float* fg_b, const float* rm_w, const float* rm_b,
    const float* wk_w, const float* wk_b, const float* ws_w, const float* ws_b,
    const float* ev_w, const float* ev_b, const float* wv_w, const float* wv_b,
    const float* ag_w, const float* ag_b, const float* wg_w, const float* wg_b) {
  int i = blockIdx.x * 256 + threadIdx.x;
  if (i >= 471 * 32) return;
  int o = i >> 5, b = i & 31;
  const float* w;
  float bias;
  if (o < 256)      { int wi = o >> 2, hh = o & 3; w = rk_w + (long)(hh * 64 + wi) * 1024; bias = rk_b[hh * 64 + wi]; }
  else if (o < 260) { int q = o - 256; w = rs_w + (long)q * 1024; bias = rs_b[q]; }
  else if (o < 264) { int q = o - 260; w = fg_w + (long)q * 1024; bias = fg_b[q]; }
  else if (o < 276) { int q = o - 264, m = q >> 2, hh = q & 3; w = rm_w + (long)(hh * 3 + m) * 1024; bias = rm_b[hh * 3 + m]; }
  else if (o < 340) { int q = o - 276; w = wk_w + (long)q * 1024; bias = wk_b[q]; }
  else if (o == 340){ w = ws_w; bias = ws_b[0]; }
  else if (o < 405) { int q = o - 341; w = ev_w + (long)q * 1024; bias = ev_b[q]; }
  else if (o < 469) { int q = o - 405; w = wv_w + (long)q * 1024; bias = wv_b[q]; }
  else if (o == 469){ w = ag_w; bias = ag_b[0]; }
  else              { w = wg_w; bias = wg_b[0]; }
  const float* h = ws + OFF_H + (long)((t + 1) & 1) * 32768 + b * 1024;
  float sum = 0.f;
#pragma unroll 4
  for (int k = 0; k < 1024; k += 4) {
    float4 a = *(const float4*)(h + k);
    float4 ww = *(const float4*)(w + k);
    sum += a.x * ww.x + a.y * ww.y + a.z * ww.z + a.w * ww.w;
  }
  ws[OFF_PROJ + b * 512 + o] = sum + bias;
}

// ===== block reductions over 128 threads =====
__device__ __forceinline__ float blk_max(float v, float* red, int n) {
  red[n] = v; __syncthreads();
#pragma unroll
  for (int s = 64; s > 0; s >>= 1) { if (n < s) red[n] = fmaxf(red[n], red[n + s]); __syncthreads(); }
  float r = red[0]; __syncthreads();
  return r;
}
__device__ __forceinline__ float blk_sum(float v, float* red, int n) {
  red[n] = v; __syncthreads();
#pragma unroll
  for (int s = 64; s > 0; s >>= 1) { if (n < s) red[n] += red[n + s]; __syncthreads(); }
  float r = red[0]; __syncthreads();
  return r;
}

// ===== memA: usage, sort, allocation, write attention, ww, p, mem+=, links =
__global__ __launch_bounds__(128) void memA_kernel(float* __restrict__ ws) {
  __shared__ float su[128], lg[128], red[128], wwl[128], pl[128];
  __shared__ float kwl[64], knl[64], dl[64];
  int b = blockIdx.x, n = threadIdx.x;
  const float* pj = ws + OFF_PROJ + b * 512;
  float* u   = ws + OFF_U  + b * 128;
  float* wwp = ws + OFF_WW + b * 128;
  float* pp  = ws + OFF_P  + b * 128;
  const float* rwp = ws + OFF_RW + b * 512;
  float* memp = ws + OFF_MEM + (long)b * 8192;
  float* lk   = ws + OFF_LINKS + (long)b * 16384;

  float fg0 = sigm(pj[260]), fg1 = sigm(pj[261]), fg2 = sigm(pj[262]), fg3 = sigm(pj[263]);
  float r0 = rwp[n * 4], r1 = rwp[n * 4 + 1], r2 = rwp[n * 4 + 2], r3 = rwp[n * 4 + 3];
  float psi = expf(logf(1.f - fg0 * r0) + logf(1.f - fg1 * r1) +
                   logf(1.f - fg2 * r2) + logf(1.f - fg3 * r3));
  float uu = u[n], wwo = wwp[n];
  uu = (uu + wwo - uu * wwo) * psi;
  u[n] = uu;
  su[n] = uu;
  if (n < 64) {
    kwl[n] = pj[276 + n];
    dl[n] = sigm(pj[405 + n]) - sigm(pj[341 + n]);  // writev - erase
  }
  __syncthreads();
  float kn2 = 0.f;
#pragma unroll
  for (int w = 0; w < 64; ++w) kn2 += kwl[w] * kwl[w];
  float kn = sqrtf(kn2);
  if (n < 64) knl[n] = kwl[n] / kn;
  // odd-even transposition sort (ascending)
  for (int ph = 0; ph < 128; ++ph) {
    int odd = ph & 1;
    int partner = (((n ^ odd) & 1) == 0) ? n + 1 : n - 1;
    float mine = su[n];
    float other = (partner >= 0 && partner < 128) ? su[partner] : mine;
    __syncthreads();
    float nv;
    if (partner < 0 || partner > 127) nv = mine;
    else if (partner > n)             nv = fminf(mine, other);
    else                              nv = fmaxf(mine, other);
    su[n] = nv;
    __syncthreads();
  }
  lg[n] = logf(su[n]);
  __syncthreads();
  if (n == 0) {
    float run = 0.f;
    for (int i = 0; i < 128; ++i) { run += lg[i]; lg[i] = run; }
  }
  __syncthreads();
  float a_n = (1.f - su[n]) * expf(lg[n] - logf(su[n]));
  float mrow[64];
  float sq = 0.f;
#pragma unroll
  for (int w = 0; w < 64; ++w) { float m = memp[n * 64 + w]; mrow[w] = m; sq += m * m; }
  float den = sqrtf(sq) + EPSF;
#pragma unroll
  for (int w = 0; w < 64; ++w) mrow[w] = mrow[w] / den;
  float dot = 0.f;
#pragma unroll
  for (int w = 0; w < 64; ++w) dot += mrow[w] * knl[w];
  float score = dot * oneplus_(pj[340]);
  float mx = blk_max(score, red, n);
  float e = expf(score - mx);
  float cw = e / blk_sum(e, red, n);
  float ag = sigm(pj[469]), wg = sigm(pj[470]);
  float wwn = wg * (ag * a_n + (1.f - ag) * cw);
  wwp[n] = wwn; wwl[n] = wwn;
  float sumww = blk_sum(wwn, red, n);
  float pn = (1.f - sumww) * pp[n] + wwn;
  pp[n] = pn; pl[n] = pn;
  __syncthreads();
#pragma unroll
  for (int w = 0; w < 64; ++w) memp[n * 64 + w] = mrow[w] + wwn * dl[w];
  for (int k2 = 0; k2 < 128; ++k2) {
    long idx = (long)k2 * 128 + n;
    float v = lk[idx] * (1.f - (wwl[k2] + wwl[n])) + wwl[k2] * pl[n];
    lk[idx] = (k2 == n) ? 0.f : v;
  }
}

// ===== memB: renormalize mem, read attention, f/b via links, new rw ========
__global__ __launch_bounds__(128) void memB_kernel(float* __restrict__ ws) {
  __shared__ float red[128], rwold[128 * 4], kl[64 * 4];
  int b = blockIdx.x, n = threadIdx.x;
  const float* pj = ws + OFF_PROJ + b * 512;
  float* rwp = ws + OFF_RW + b * 512;
  float* memp = ws + OFF_MEM + (long)b * 8192;
  const float* lk = ws + OFF_LINKS + (long)b * 16384;
#pragma unroll
  for (int h = 0; h < 4; ++h) rwold[n * 4 + h] = rwp[n * 4 + h];
  if (n < 64) {
#pragma unroll
    for (int h = 0; h < 4; ++h) kl[n * 4 + h] = pj[n * 4 + h];
  }
  __syncthreads();
  float mrow[64];
  float sq = 0.f;
#pragma unroll
  for (int w = 0; w < 64; ++w) { float m = memp[n * 64 + w]; mrow[w] = m; sq += m * m; }
  float den2 = sqrtf(sq) + EPSF;
#pragma unroll
  for (int w = 0; w < 64; ++w) { mrow[w] = mrow[w] / den2; memp[n * 64 + w] = mrow[w]; }
  float cr_[4];
#pragma unroll
  for (int h = 0; h < 4; ++h) {
    float s3 = 0.f;
#pragma unroll
    for (int w = 0; w < 64; ++w) { float kv = kl[w * 4 + h]; s3 += kv * kv; }
    float knh = sqrtf(s3);
    float d2 = 0.f;
#pragma unroll
    for (int w = 0; w < 64; ++w) d2 += mrow[w] * (kl[w * 4 + h] / knh);
    float sc = d2 * oneplus_(pj[256 + h]);
    float mxh = blk_max(sc, red, n);
    float eh = expf(sc - mxh);
    cr_[h] = eh / blk_sum(eh, red, n);
  }
  float f0 = 0, f1 = 0, f2 = 0, f3 = 0, b0 = 0, b1 = 0, b2 = 0, b3 = 0;
  for (int j = 0; j < 128; ++j) {
    float lrow = lk[(long)n * 128 + j];
    float lcol = lk[(long)j * 128 + n];
    float q0 = rwold[j * 4], q1 = rwold[j * 4 + 1], q2 = rwold[j * 4 + 2], q3 = rwold[j * 4 + 3];
    f0 += lrow * q0; f1 += lrow * q1; f2 += lrow * q2; f3 += lrow * q3;
    b0 += lcol * q0; b1 += lcol * q1; b2 += lcol * q2; b3 += lcol * q3;
  }
  float fv[4] = {f0, f1, f2, f3}, bv[4] = {b0, b1, b2, b3};
#pragma unroll
  for (int h = 0; h < 4; ++h) {
    float m0 = pj[264 + h], m1 = pj[264 + 4 + h], m2 = pj[264 + 8 + h];
    float mm = fmaxf(m0, fmaxf(m1, m2));
    float e0 = expf(m0 - mm), e1 = expf(m1 - mm), e2 = expf(m2 - mm);
    float inv = 1.f / (e0 + e1 + e2);
    rwp[n * 4 + h] = (e0 * inv) * bv[h] + (e1 * inv) * cr_[h] + (e2 * inv) * fv[h];
  }
}

// ===== memC: rv = mem^T @ rw_new ===========================================
__global__ __launch_bounds__(128) void memC_kernel(int t, float* __restrict__ ws) {
  __shared__ float rwl[512];
  int b = blockIdx.x, n = threadIdx.x;
  const float* rwp = ws + OFF_RW + b * 512;
  const float* memp = ws + OFF_MEM + (long)b * 8192;
  rwl[n] = rwp[n]; rwl[128 + n] = rwp[128 + n];
  rwl[256 + n] = rwp[256 + n]; rwl[384 + n] = rwp[384 + n];
  __syncthreads();
  int w2 = n & 63, which = n >> 6;
  float rv0 = 0.f, rv1 = 0.f;
  for (int j = 0; j < 128; ++j) {
    float mv = memp[j * 64 + w2];
    rv0 += mv * rwl[j * 4 + which * 2];
    rv1 += mv * rwl[j * 4 + which * 2 + 1];
  }
  float* RVp = ws + OFF_RV + (long)((t + 1) & 1) * 8192 + b * 256;
  RVp[w2 * 4 + which * 2]     = rv0;
  RVp[w2 * 4 + which * 2 + 1] = rv1;
}

// ===== ostep: per-step y = h@Why^T + b + rv@Wry^T, FLOAT32 to d_out ========
__global__ __launch_bounds__(256) void ostep_kernel(
    int t, const float* __restrict__ ws, const float* __restrict__ Why_w,
    const float* __restrict__ Why_b, const float* __restrict__ Wry_w,
    float* __restrict__ out) {
  __shared__ float xs[32][132];
  int tid = threadIdx.x;
  int col = blockIdx.x * 64 + (tid & 63);
  int bq = tid >> 6;               // 0..3 -> rows bq*8..bq*8+7
  const float* Hc  = ws + OFF_H  + (long)((t + 1) & 1) * 32768;
  const float* RVc = ws + OFF_RV + (long)((t + 1) & 1) * 8192;
  float acc[8];
#pragma unroll
  for (int r = 0; r < 8; ++r) acc[r] = 0.f;
  for (int kt = 0; kt < 10; ++kt) {
    __syncthreads();
#pragma unroll
    for (int q = 0; q < 16; ++q) {
      int idx = q * 256 + tid;            // 0..4095
      int bb = idx >> 7, kk = idx & 127;
      int gk = kt * 128 + kk;
      xs[bb][kk] = (gk < 1024) ? Hc[bb * 1024 + gk] : RVc[bb * 256 + gk - 1024];
    }
    __syncthreads();
    const float* wp = (kt < 8) ? (Why_w + (long)col * 1024 + kt * 128)
                               : (Wry_w + (long)col * 256 + (kt - 8) * 128);
#pragma unroll 8
    for (int k = 0; k < 128; k += 4) {
      float4 w = *(const float4*)(wp + k);
#pragma unroll
      for (int r = 0; r < 8; ++r) {
        int row = bq * 8 + r;
        acc[r] += xs[row][k] * w.x + xs[row][k + 1] * w.y +
                  xs[row][k + 2] * w.z + xs[row][k + 3] * w.w;
      }
    }
  }
  float bias = Why_b[col];
  float* ob = out + (long)t * 512000 + col;
#pragma unroll
  for (int r = 0; r < 8; ++r) {
    ob[(long)(bq * 8 + r) * 16000] = acc[r] + bias;
  }
}

extern "C" void kernel_launch(void* const* d_in, const int* in_sizes, int n_in,
                              void* d_out, int out_size, void* d_ws, size_t ws_size,
                              hipStream_t stream) {
  const void* src_raw = d_in[0];
  const float* emb   = (const float*)d_in[1];
  const float* W_ih  = (const float*)d_in[2];
  const float* W_hh  = (const float*)d_in[3];
  const float* b_ih  = (const float*)d_in[4];
  const float* b_hh  = (const float*)d_in[5];
  const float* rk_w  = (const float*)d_in[6];
  const float* rk_b  = (const float*)d_in[7];
  const float* rs_w  = (const float*)d_in[8];
  const float* rs_b  = (const float*)d_in[9];
  const float* fg_w  = (const float*)d_in[10];
  const float* fg_b  = (const float*)d_in[11];
  const float* rm_w  = (const float*)d_in[12];
  const float* rm_b  = (const float*)d_in[13];
  const float* wk_w  = (const float*)d_in[14];
  const float* wk_b  = (const float*)d_in[15];
  const float* ws_w  = (const float*)d_in[16];
  const float* ws_b  = (const float*)d_in[17];
  const float* ev_w  = (const float*)d_in[18];
  const float* ev_b  = (const float*)d_in[19];
  const float* wv_w  = (const float*)d_in[20];
  const float* wv_b  = (const float*)d_in[21];
  const float* ag_w  = (const float*)d_in[22];
  const float* ag_b  = (const float*)d_in[23];
  const float* wg_w  = (const float*)d_in[24];
  const float* wg_b  = (const float*)d_in[25];
  const float* Why_w = (const float*)d_in[26];
  const float* Why_b = (const float*)d_in[27];
  const float* Wry_w = (const float*)d_in[28];
  float* ws = (float*)d_ws;
  float* out = (float*)d_out;

  src_decode<<<1, 256, 0, stream>>>(src_raw, ws);
  init_kernel<<<512, 256, 0, stream>>>(ws);
  for (int t = 0; t < TN; ++t) {
    gates_naive<<<512, 256, 0, stream>>>(t, emb, W_ih, W_hh, b_ih, b_hh, ws);
    lstm_kernel<<<128, 256, 0, stream>>>(t, ws);
    proj_naive<<<59, 256, 0, stream>>>(t, ws, rk_w, rk_b, rs_w, rs_b, fg_w, fg_b,
                                       rm_w, rm_b, wk_w, wk_b, ws_w, ws_b,
                                       ev_w, ev_b, wv_w, wv_b, ag_w, ag_b, wg_w, wg_b);
    memA_kernel<<<32, 128, 0, stream>>>(ws);
    memB_kernel<<<32, 128, 0, stream>>>(ws);
    memC_kernel<<<32, 128, 0, stream>>>(t, ws);
    ostep_kernel<<<250, 256, 0, stream>>>(t, ws, Why_w, Why_b, Wry_w, out);
  }
}

// Round 7
// 14588.504 us; speedup vs baseline: 1.5220x; 1.5220x over previous
//
#include <hip/hip_runtime.h>
#include <math.h>

// ---- problem dims ----
#define TN 64
#define BN 32
#define EPSF 1e-6f

// ---- workspace layout (floats): full H/RV history for deferred out-GEMM ----
constexpr long OFF_H     = 0;                       // 65 * 32*1024
constexpr long OFF_RV    = OFF_H    + 65L*32768;    // 65 * 32*256
constexpr long OFF_S     = OFF_RV   + 65L*8192;     // 32768
constexpr long OFF_RW    = OFF_S    + 32768;        // B*N*HD = 16384
constexpr long OFF_WW    = OFF_RW   + 16384;        // B*N
constexpr long OFF_U     = OFF_WW   + 4096;
constexpr long OFF_P     = OFF_U    + 4096;
constexpr long OFF_MEM   = OFF_P    + 4096;         // B*N*WD = 262144
constexpr long OFF_LINKS = OFF_MEM  + 262144;       // B*N*N = 524288
constexpr long OFF_PROJ  = OFF_LINKS+ 524288;       // B*512 (471 used)
constexpr long OFF_SRC   = OFF_PROJ + 16384;        // 2048 ints
// total ≈ 14.1 MB (rounds 1-3 used this footprint without corruption)

__device__ __forceinline__ float sigm(float x) { return 1.f / (1.f + expf(-x)); }
__device__ __forceinline__ float oneplus_(float x) {
  return 1.f + fmaxf(x, 0.f) + log1pf(expf(-fabsf(x)));
}

// ===== src width auto-detect + decode to int32 (validated round 6) =========
__global__ void src_decode(const void* __restrict__ src_raw, float* __restrict__ ws) {
  __shared__ int is64_s;
  if (threadIdx.x == 0) is64_s = 1;
  __syncthreads();
  const long long* s64 = (const long long*)src_raw;
  for (int i = threadIdx.x; i < 1024; i += 256) {
    long long v = s64[i];
    if (v < 0 || v >= 32000) is64_s = 0;
  }
  __syncthreads();
  int* dst = (int*)(ws + OFF_SRC);
  if (is64_s) {
    for (int i = threadIdx.x; i < 2048; i += 256) dst[i] = (int)s64[i];
  } else {
    const int* s32 = (const int*)src_raw;
    for (int i = threadIdx.x; i < 2048; i += 256) dst[i] = s32[i];
  }
}

// ================= init: H slot0, RV slot0, state; U=EPS ====================
__global__ void init_kernel(float* ws) {
  long i0 = (long)blockIdx.x * blockDim.x + threadIdx.x;
  long stride = (long)gridDim.x * blockDim.x;
  for (long x = i0; x < 32768; x += stride) ws[OFF_H + x] = 0.f;
  for (long x = i0; x < 8192;  x += stride) ws[OFF_RV + x] = 0.f;
  const long zlen = OFF_PROJ - OFF_S;
  for (long x = i0; x < zlen; x += stride) {
    long g = OFF_S + x;
    ws[g] = (g >= OFF_U && g < OFF_U + 4096) ? EPSF : 0.f;
  }
}

// ===== gates4: fused gates-GEMM + LSTM pointwise ===========================
// 128 blocks x 256 thr. thread: b = tid&31, jg = tid>>5; j = blk*8+jg (0..1023)
// Each thread: 4 dot-products (i,f,g,o gates for hidden j) over K=1792,
// x staged in LDS per 256-chunk; weight rows broadcast across the 32 b-lanes.
__global__ __launch_bounds__(256) void gates4_kernel(
    int t, const float* __restrict__ emb,
    const float* __restrict__ W_ih, const float* __restrict__ W_hh,
    const float* __restrict__ b_ih, const float* __restrict__ b_hh,
    float* __restrict__ ws) {
  __shared__ float xl[32 * 260];
  int tid = threadIdx.x;
  int b = tid & 31, jg = tid >> 5;
  int j = blockIdx.x * 8 + jg;
  const int* src = (const int*)(ws + OFF_SRC);
  float acc0 = 0.f, acc1 = 0.f, acc2 = 0.f, acc3 = 0.f;
  for (int c = 0; c < 7; ++c) {
    __syncthreads();
#pragma unroll
    for (int q = 0; q < 32; ++q) {
      int i2 = q * 256 + tid;
      int bb = i2 >> 8, kk = i2 & 255;
      float v;
      if (c < 2)       v = emb[(long)src[t * 32 + bb] * 512 + c * 256 + kk];
      else if (c == 2) v = ws[OFF_RV + (long)t * 8192 + bb * 256 + kk];
      else             v = ws[OFF_H + (long)t * 32768 + bb * 1024 + (c - 3) * 256 + kk];
      xl[bb * 260 + kk] = v;
    }
    __syncthreads();
    const float* xp = &xl[b * 260];
    const float *w0, *w1, *w2, *w3;
    if (c < 3) {
      w0 = W_ih + (long)j * 768 + c * 256;
      w1 = W_ih + (long)(1024 + j) * 768 + c * 256;
      w2 = W_ih + (long)(2048 + j) * 768 + c * 256;
      w3 = W_ih + (long)(3072 + j) * 768 + c * 256;
    } else {
      w0 = W_hh + (long)j * 1024 + (c - 3) * 256;
      w1 = W_hh + (long)(1024 + j) * 1024 + (c - 3) * 256;
      w2 = W_hh + (long)(2048 + j) * 1024 + (c - 3) * 256;
      w3 = W_hh + (long)(3072 + j) * 1024 + (c - 3) * 256;
    }
#pragma unroll 4
    for (int k = 0; k < 256; k += 4) {
      float4 xv = *(const float4*)(xp + k);
      float4 a = *(const float4*)(w0 + k);
      float4 bb4 = *(const float4*)(w1 + k);
      float4 cc4 = *(const float4*)(w2 + k);
      float4 dd4 = *(const float4*)(w3 + k);
      acc0 += xv.x * a.x + xv.y * a.y + xv.z * a.z + xv.w * a.w;
      acc1 += xv.x * bb4.x + xv.y * bb4.y + xv.z * bb4.z + xv.w * bb4.w;
      acc2 += xv.x * cc4.x + xv.y * cc4.y + xv.z * cc4.z + xv.w * cc4.w;
      acc3 += xv.x * dd4.x + xv.y * dd4.y + xv.z * dd4.z + xv.w * dd4.w;
    }
  }
  float gi = acc0 + b_ih[j]        + b_hh[j];
  float gf = acc1 + b_ih[1024 + j] + b_hh[1024 + j];
  float gg = acc2 + b_ih[2048 + j] + b_hh[2048 + j];
  float go = acc3 + b_ih[3072 + j] + b_hh[3072 + j];
  long si = (long)b * 1024 + j;
  float sv = sigm(gf) * ws[OFF_S + si] + sigm(gi) * tanhf(gg);
  ws[OFF_S + si] = sv;
  ws[OFF_H + (long)(t + 1) * 32768 + si] = sigm(go) * tanhf(sv);
}

// ===== proj: wave-per-output, float4 loads + shfl_xor reduce ===============
__global__ __launch_bounds__(256) void proj_kernel(
    int t, float* __restrict__ ws,
    const float* rk_w, const float* rk_b, const float* rs_w, const float* rs_b,
    const float* fg_w, const float* fg_b, const float* rm_w, const float* rm_b,
    const float* wk_w, const float* wk_b, const float* ws_w, const float* ws_b,
    const float* ev_w, const float* ev_b, const float* wv_w, const float* wv_b,
    const float* ag_w, const float* ag_b, const float* wg_w, const float* wg_b) {
  int wid = blockIdx.x * 4 + (threadIdx.x >> 6);  // 0..15071
  int lane = threadIdx.x & 63;
  int o = wid >> 5, b = wid & 31;
  const float* w;
  float bias;
  if (o < 256)      { int wi = o >> 2, hh = o & 3; w = rk_w + (long)(hh * 64 + wi) * 1024; bias = rk_b[hh * 64 + wi]; }
  else if (o < 260) { int q = o - 256; w = rs_w + (long)q * 1024; bias = rs_b[q]; }
  else if (o < 264) { int q = o - 260; w = fg_w + (long)q * 1024; bias = fg_b[q]; }
  else if (o < 276) { int q = o - 264, m = q >> 2, hh = q & 3; w = rm_w + (long)(hh * 3 + m) * 1024; bias = rm_b[hh * 3 + m]; }
  else if (o < 340) { int q = o - 276; w = wk_w + (long)q * 1024; bias = wk_b[q]; }
  else if (o == 340){ w = ws_w; bias = ws_b[0]; }
  else if (o < 405) { int q = o - 341; w = ev_w + (long)q * 1024; bias = ev_b[q]; }
  else if (o < 469) { int q = o - 405; w = wv_w + (long)q * 1024; bias = wv_b[q]; }
  else if (o == 469){ w = ag_w; bias = ag_b[0]; }
  else              { w = wg_w; bias = wg_b[0]; }
  const float* hp = ws + OFF_H + (long)(t + 1) * 32768 + b * 1024 + lane * 16;
  const float* wp = w + lane * 16;
  float s = 0.f;
#pragma unroll
  for (int m = 0; m < 16; m += 4) {
    float4 a = *(const float4*)(hp + m);
    float4 wv = *(const float4*)(wp + m);
    s += a.x * wv.x + a.y * wv.y + a.z * wv.z + a.w * wv.w;
  }
#pragma unroll
  for (int off = 32; off; off >>= 1) s += __shfl_xor(s, off);
  if (lane == 0) ws[OFF_PROJ + b * 512 + o] = s + bias;
}

// ===== block reductions over 128 threads =====
__device__ __forceinline__ float blk_max(float v, float* red, int n) {
  red[n] = v; __syncthreads();
#pragma unroll
  for (int s = 64; s > 0; s >>= 1) { if (n < s) red[n] = fmaxf(red[n], red[n + s]); __syncthreads(); }
  float r = red[0]; __syncthreads();
  return r;
}
__device__ __forceinline__ float blk_sum(float v, float* red, int n) {
  red[n] = v; __syncthreads();
#pragma unroll
  for (int s = 64; s > 0; s >>= 1) { if (n < s) red[n] += red[n + s]; __syncthreads(); }
  float r = red[0]; __syncthreads();
  return r;
}

// ===== memA: usage, bitonic sort, allocation, write attn, ww, p, mem, links
__global__ __launch_bounds__(128) void memA_kernel(float* __restrict__ ws) {
  __shared__ float su[128], lg[128], red[128], wwl[128], pl[128];
  __shared__ float kwl[64], knl[64], dl[64];
  int b = blockIdx.x, n = threadIdx.x;
  const float* pj = ws + OFF_PROJ + b * 512;
  float* u   = ws + OFF_U  + b * 128;
  float* wwp = ws + OFF_WW + b * 128;
  float* pp  = ws + OFF_P  + b * 128;
  const float* rwp = ws + OFF_RW + b * 512;
  float* memp = ws + OFF_MEM + (long)b * 8192;
  float* lk   = ws + OFF_LINKS + (long)b * 16384;

  float fg0 = sigm(pj[260]), fg1 = sigm(pj[261]), fg2 = sigm(pj[262]), fg3 = sigm(pj[263]);
  float r0 = rwp[n * 4], r1 = rwp[n * 4 + 1], r2 = rwp[n * 4 + 2], r3 = rwp[n * 4 + 3];
  float psi = expf(logf(1.f - fg0 * r0) + logf(1.f - fg1 * r1) +
                   logf(1.f - fg2 * r2) + logf(1.f - fg3 * r3));
  float uu = u[n], wwo = wwp[n];
  uu = (uu + wwo - uu * wwo) * psi;
  u[n] = uu;
  su[n] = uu;
  if (n < 64) {
    kwl[n] = pj[276 + n];
    dl[n] = sigm(pj[405 + n]) - sigm(pj[341 + n]);  // writev - erase
  }
  __syncthreads();
  float kn2 = 0.f;
#pragma unroll
  for (int w = 0; w < 64; ++w) kn2 += kwl[w] * kwl[w];
  float kn = sqrtf(kn2);
  if (n < 64) knl[n] = kwl[n] / kn;
  // bitonic ascending sort (validated round 1: identical downstream results)
  for (int k = 2; k <= 128; k <<= 1) {
    for (int jj = k >> 1; jj > 0; jj >>= 1) {
      int ixj = n ^ jj;
      if (ixj > n) {
        float a1 = su[n], a2 = su[ixj];
        if (((n & k) == 0) ? (a1 > a2) : (a1 < a2)) { su[n] = a2; su[ixj] = a1; }
      }
      __syncthreads();
    }
  }
  // Hillis-Steele inclusive scan of logs (validated round 1)
  lg[n] = logf(su[n]);
  __syncthreads();
  for (int off = 1; off < 128; off <<= 1) {
    float v = (n >= off) ? lg[n - off] : 0.f;
    __syncthreads();
    lg[n] += v;
    __syncthreads();
  }
  float a_n = (1.f - su[n]) * expf(lg[n] - logf(su[n]));
  float mrow[64];
  float sq = 0.f;
#pragma unroll
  for (int w = 0; w < 64; ++w) { float m = memp[n * 64 + w]; mrow[w] = m; sq += m * m; }
  float den = sqrtf(sq) + EPSF;
#pragma unroll
  for (int w = 0; w < 64; ++w) mrow[w] = mrow[w] / den;
  float dot = 0.f;
#pragma unroll
  for (int w = 0; w < 64; ++w) dot += mrow[w] * knl[w];
  float score = dot * oneplus_(pj[340]);
  float mx = blk_max(score, red, n);
  float e = expf(score - mx);
  float cw = e / blk_sum(e, red, n);
  float ag = sigm(pj[469]), wg = sigm(pj[470]);
  float wwn = wg * (ag * a_n + (1.f - ag) * cw);
  wwp[n] = wwn; wwl[n] = wwn;
  float sumww = blk_sum(wwn, red, n);
  float pn = (1.f - sumww) * pp[n] + wwn;
  pp[n] = pn; pl[n] = pn;
  __syncthreads();
#pragma unroll
  for (int w = 0; w < 64; ++w) memp[n * 64 + w] = mrow[w] + wwn * dl[w];
  for (int k2 = 0; k2 < 128; ++k2) {
    long idx = (long)k2 * 128 + n;
    float v = lk[idx] * (1.f - (wwl[k2] + wwl[n])) + wwl[k2] * pl[n];
    lk[idx] = (k2 == n) ? 0.f : v;
  }
}

// ===== memBC: renorm mem, read attn, f/b, new rw, rv (mem+rw via LDS) ======
__global__ __launch_bounds__(128) void memBC_kernel(int t, float* __restrict__ ws) {
  __shared__ float red[128], rwold[512], rwnew[512], kl[256];
  __shared__ float mem_s[128 * 64];
  int b = blockIdx.x, n = threadIdx.x;
  const float* pj = ws + OFF_PROJ + b * 512;
  float* rwp = ws + OFF_RW + b * 512;
  float* memp = ws + OFF_MEM + (long)b * 8192;
  const float* lk = ws + OFF_LINKS + (long)b * 16384;
#pragma unroll
  for (int h = 0; h < 4; ++h) rwold[n * 4 + h] = rwp[n * 4 + h];
  if (n < 64) {
#pragma unroll
    for (int h = 0; h < 4; ++h) kl[n * 4 + h] = pj[n * 4 + h];
  }
  __syncthreads();
  float mrow[64];
  float sq = 0.f;
#pragma unroll
  for (int w = 0; w < 64; ++w) { float m = memp[n * 64 + w]; mrow[w] = m; sq += m * m; }
  float den2 = sqrtf(sq) + EPSF;
#pragma unroll
  for (int w = 0; w < 64; ++w) {
    mrow[w] = mrow[w] / den2;
    memp[n * 64 + w] = mrow[w];
    mem_s[n * 64 + w] = mrow[w];
  }
  float cr_[4];
#pragma unroll
  for (int h = 0; h < 4; ++h) {
    float s3 = 0.f;
#pragma unroll
    for (int w = 0; w < 64; ++w) { float kv = kl[w * 4 + h]; s3 += kv * kv; }
    float knh = sqrtf(s3);
    float d2 = 0.f;
#pragma unroll
    for (int w = 0; w < 64; ++w) d2 += mrow[w] * (kl[w * 4 + h] / knh);
    float sc = d2 * oneplus_(pj[256 + h]);
    float mxh = blk_max(sc, red, n);
    float eh = expf(sc - mxh);
    cr_[h] = eh / blk_sum(eh, red, n);
  }
  float f0 = 0, f1 = 0, f2 = 0, f3 = 0, b0 = 0, b1 = 0, b2 = 0, b3 = 0;
  for (int jj = 0; jj < 128; ++jj) {
    float lrow = lk[(long)n * 128 + jj];
    float lcol = lk[(long)jj * 128 + n];
    float q0 = rwold[jj * 4], q1 = rwold[jj * 4 + 1], q2 = rwold[jj * 4 + 2], q3 = rwold[jj * 4 + 3];
    f0 += lrow * q0; f1 += lrow * q1; f2 += lrow * q2; f3 += lrow * q3;
    b0 += lcol * q0; b1 += lcol * q1; b2 += lcol * q2; b3 += lcol * q3;
  }
  float fv[4] = {f0, f1, f2, f3}, bv[4] = {b0, b1, b2, b3};
#pragma unroll
  for (int h = 0; h < 4; ++h) {
    float m0 = pj[264 + h], m1 = pj[264 + 4 + h], m2 = pj[264 + 8 + h];
    float mm = fmaxf(m0, fmaxf(m1, m2));
    float e0 = expf(m0 - mm), e1 = expf(m1 - mm), e2 = expf(m2 - mm);
    float inv = 1.f / (e0 + e1 + e2);
    float rwv = (e0 * inv) * bv[h] + (e1 * inv) * cr_[h] + (e2 * inv) * fv[h];
    rwp[n * 4 + h] = rwv;
    rwnew[n * 4 + h] = rwv;
  }
  __syncthreads();
  // rv = mem^T @ rw_new (from LDS)
  int w2 = n & 63, which = n >> 6;
  float rv0 = 0.f, rv1 = 0.f;
  for (int jj = 0; jj < 128; ++jj) {
    float mv = mem_s[jj * 64 + w2];
    rv0 += mv * rwnew[jj * 4 + which * 2];
    rv1 += mv * rwnew[jj * 4 + which * 2 + 1];
  }
  float* RVp = ws + OFF_RV + (long)(t + 1) * 8192 + b * 256;
  RVp[w2 * 4 + which * 2]     = rv0;
  RVp[w2 * 4 + which * 2 + 1] = rv1;
}

// ===== final output GEMM: [2048,16000], K=1280, fp32 out ===================
__global__ __launch_bounds__(256) void out_gemm(
    const float* __restrict__ ws, const float* __restrict__ Why_w,
    const float* __restrict__ Why_b, const float* __restrict__ Wry_w,
    float* __restrict__ out) {
  __shared__ float al[16 * 132];
  __shared__ float bl[16 * 132];
  const float* Hp  = ws + OFF_H + 32768;   // [2048][1024]
  const float* RVp = ws + OFF_RV + 8192;   // [2048][256]
  int tid = threadIdx.x;
  int tx = tid & 15, ty = tid >> 4;
  int col0 = blockIdx.x * 128, row0 = blockIdx.y * 128;
  float acc[8][8];
#pragma unroll
  for (int i = 0; i < 8; ++i)
#pragma unroll
    for (int j = 0; j < 8; ++j) acc[i][j] = 0.f;
  for (int kt = 0; kt < 80; ++kt) {
    int k0 = kt * 16;
    __syncthreads();
#pragma unroll
    for (int q = 0; q < 8; ++q) {
      int i2 = q * 256 + tid;
      int r = i2 >> 4, k = i2 & 15;
      int gk = k0 + k;
      float va = (gk < 1024) ? Hp[(long)(row0 + r) * 1024 + gk]
                             : RVp[(long)(row0 + r) * 256 + gk - 1024];
      al[k * 132 + r] = va;
      float vb = (gk < 1024) ? Why_w[(long)(col0 + r) * 1024 + gk]
                             : Wry_w[(long)(col0 + r) * 256 + gk - 1024];
      bl[k * 132 + r] = vb;
    }
    __syncthreads();
#pragma unroll
    for (int k = 0; k < 16; ++k) {
      float4 a0 = *(const float4*)&al[k * 132 + ty * 8];
      float4 a1 = *(const float4*)&al[k * 132 + ty * 8 + 4];
      float4 c0 = *(const float4*)&bl[k * 132 + tx * 8];
      float4 c1 = *(const float4*)&bl[k * 132 + tx * 8 + 4];
      float ar[8] = {a0.x, a0.y, a0.z, a0.w, a1.x, a1.y, a1.z, a1.w};
      float br[8] = {c0.x, c0.y, c0.z, c0.w, c1.x, c1.y, c1.z, c1.w};
#pragma unroll
      for (int i = 0; i < 8; ++i)
#pragma unroll
        for (int j = 0; j < 8; ++j) acc[i][j] += ar[i] * br[j];
    }
  }
  float4 bb0 = *(const float4*)&Why_b[col0 + tx * 8];
  float4 bb1 = *(const float4*)&Why_b[col0 + tx * 8 + 4];
  float bias[8] = {bb0.x, bb0.y, bb0.z, bb0.w, bb1.x, bb1.y, bb1.z, bb1.w};
#pragma unroll
  for (int i = 0; i < 8; ++i) {
    long r = row0 + ty * 8 + i;
    float* op = out + r * 16000 + col0 + tx * 8;
    float4 o0 = {acc[i][0] + bias[0], acc[i][1] + bias[1], acc[i][2] + bias[2], acc[i][3] + bias[3]};
    float4 o1 = {acc[i][4] + bias[4], acc[i][5] + bias[5], acc[i][6] + bias[6], acc[i][7] + bias[7]};
    *(float4*)op = o0;
    *(float4*)(op + 4) = o1;
  }
}

extern "C" void kernel_launch(void* const* d_in, const int* in_sizes, int n_in,
                              void* d_out, int out_size, void* d_ws, size_t ws_size,
                              hipStream_t stream) {
  const void* src_raw = d_in[0];
  const float* emb   = (const float*)d_in[1];
  const float* W_ih  = (const float*)d_in[2];
  const float* W_hh  = (const float*)d_in[3];
  const float* b_ih  = (const float*)d_in[4];
  const float* b_hh  = (const float*)d_in[5];
  const float* rk_w  = (const float*)d_in[6];
  const float* rk_b  = (const float*)d_in[7];
  const float* rs_w  = (const float*)d_in[8];
  const float* rs_b  = (const float*)d_in[9];
  const float* fg_w  = (const float*)d_in[10];
  const float* fg_b  = (const float*)d_in[11];
  const float* rm_w  = (const float*)d_in[12];
  const float* rm_b  = (const float*)d_in[13];
  const float* wk_w  = (const float*)d_in[14];
  const float* wk_b  = (const float*)d_in[15];
  const float* ws_w  = (const float*)d_in[16];
  const float* ws_b  = (const float*)d_in[17];
  const float* ev_w  = (const float*)d_in[18];
  const float* ev_b  = (const float*)d_in[19];
  const float* wv_w  = (const float*)d_in[20];
  const float* wv_b  = (const float*)d_in[21];
  const float* ag_w  = (const float*)d_in[22];
  const float* ag_b  = (const float*)d_in[23];
  const float* wg_w  = (const float*)d_in[24];
  const float* wg_b  = (const float*)d_in[25];
  const float* Why_w = (const float*)d_in[26];
  const float* Why_b = (const float*)d_in[27];
  const float* Wry_w = (const float*)d_in[28];
  float* ws = (float*)d_ws;
  float* out = (float*)d_out;

  src_decode<<<1, 256, 0, stream>>>(src_raw, ws);
  init_kernel<<<512, 256, 0, stream>>>(ws);
  for (int t = 0; t < TN; ++t) {
    gates4_kernel<<<128, 256, 0, stream>>>(t, emb, W_ih, W_hh, b_ih, b_hh, ws);
    proj_kernel<<<3768, 256, 0, stream>>>(t, ws, rk_w, rk_b, rs_w, rs_b, fg_w, fg_b,
                                          rm_w, rm_b, wk_w, wk_b, ws_w, ws_b,
                                          ev_w, ev_b, wv_w, wv_b, ag_w, ag_b, wg_w, wg_b);
    memA_kernel<<<32, 128, 0, stream>>>(ws);
    memBC_kernel<<<32, 128, 0, stream>>>(t, ws);
  }
  out_gemm<<<dim3(125, 16), 256, 0, stream>>>(ws, Why_w, Why_b, Wry_w, out);
}